// Round 1
// 377.191 us; speedup vs baseline: 1.0213x; 1.0213x over previous
//
#include <hip/hip_runtime.h>
#include <hip/hip_bf16.h>

// AttentionWithContext: out[b,f] = sum_t a[b,t] x[b,t,f],
//   a = exp(ait)/(sum_t exp(ait) + 1e-7),  ait = tanh(x@W + bias) . u
// R5: prep kernel eliminated (A-fragments loaded straight from fp32 W with
// in-register cvt_pk RNE; one full W pass per block, L2-resident), and the
// atomicAdd epilogue replaced by per-block partials (nump[512][256], denp[512])
// reduced in finalize -- no workspace zero-init needed, no prep->attn graph
// dependency. Main loop unchanged R4 async-DMA pipeline: 512 blocks (2/CU),
// fp32 x tiles staged to LDS via global_load_lds width-16, double-buffered,
// raw s_barrier + manual s_waitcnt vmcnt(8) keeps next tile's DMAs in flight
// across the barrier. tanh folded to fma/exp2/add/rcp/fma (bias pre-scaled
// by 2*log2e into the fma addend).

#define BB 128
#define TT 2048
#define FF 256
#define TQ 32                  // timesteps per tile
#define NT 16                  // tiles per block
#define NBLK (BB * (TT / (TQ * NT)))   // 128 * 4 = 512 blocks = 2/CU
#define RS 260                 // LDS row stride in fp32 elems (256 + 4 pad = 1040 B)

// s_waitcnt imms: vmcnt[3:0]|[15:14], expcnt[6:4], lgkmcnt[11:8]
#define W_VM8   0x0F78         // vmcnt(8),  lgkm/exp no-wait
#define W_VM0   0x0F70         // vmcnt(0),  lgkm/exp no-wait
#define W_LGKM0 0xC07F         // lgkmcnt(0), vm/exp no-wait

using bf16x8 = __attribute__((ext_vector_type(8))) short;
using f32x4  = __attribute__((ext_vector_type(4))) float;

typedef __attribute__((address_space(1))) const void* as1cv;
typedef __attribute__((address_space(3))) void* as3v;

__device__ __forceinline__ unsigned pk2bf(float a, float b) {
  __hip_bfloat162 h = __float22bfloat162_rn(make_float2(a, b));  // v_cvt_pk_bf16_f32 (RNE)
  union { __hip_bfloat162 h; unsigned u; } v; v.h = h;
  return v.u;
}

template <int IMM>
__device__ __forceinline__ void wait_barrier() {
  asm volatile("" ::: "memory");
  __builtin_amdgcn_s_waitcnt(IMM);
  __builtin_amdgcn_s_barrier();
  asm volatile("" ::: "memory");
}

// ---------------- main fused kernel ----------------
__global__ __launch_bounds__(256, 2)
void attn_main(const float* __restrict__ x, const float* __restrict__ W,
               const float* __restrict__ bias, const float* __restrict__ uvec,
               float* __restrict__ nump, float* __restrict__ denp) {
  __shared__ float xb[2][TQ * RS];     // 2 x 33280 B fp32 staging
  __shared__ float part[4][TQ];        // per-wave g-partials of ait

  const int tid  = threadIdx.x;
  const int wave = tid >> 6;
  const int lane = tid & 63;
  const int q    = lane >> 4;          // quad
  const int ln   = lane & 15;
  const int b    = blockIdx.x >> 2;    // batch row
  const int seg  = blockIdx.x & 3;     // 512-t segment
  const float* xt = x + ((long)b * TT + (long)seg * (NT * TQ)) * FF;
  const int gbase = wave * 64;

  // ---- issue tile 0 staging DMAs first (8 rows/wave, 1 KB each) ----
  {
    const float* gp = xt + lane * 4;
    #pragma unroll
    for (int r = 0; r < 8; ++r) {
      int row = wave * 8 + r;
      __builtin_amdgcn_global_load_lds((as1cv)(const void*)(gp + row * FF),
                                       (as3v)(void*)(&xb[0][row * RS]), 16, 0, 0);
    }
  }

  // ---- A-fragments straight from fp32 W (no prep kernel):
  // afr[kk][gt] elem j = bf16(W[kk*32 + q*8 + j][gbase + gt*16 + ln]).
  // Column-strided scalar loads; whole block reads W exactly once (256 KB,
  // L2-resident); latency hides under the tile-0 DMAs. 128 VGPRs persistent.
  bf16x8 afr[8][4];
  #pragma unroll
  for (int kk = 0; kk < 8; ++kk)
    #pragma unroll
    for (int gt = 0; gt < 4; ++gt) {
      const float* wp = W + (kk * 32 + q * 8) * FF + (gbase + gt * 16 + ln);
      union { bf16x8 v; unsigned u[4]; } aa;
      #pragma unroll
      for (int jj = 0; jj < 4; ++jj)
        aa.u[jj] = pk2bf(wp[(2 * jj) * FF], wp[(2 * jj + 1) * FF]);
      afr[kk][gt] = aa.v;
    }

  // ---- per-lane epilogue constants ----
  // tanh(v)*u summed: ait = su + sum_g m2u[g] * rcp(exp2(fma(acc, K2, bi2[g])) + 1)
  const float K2 = 2.8853900817779268f;   // 2*log2(e)
  float bi2[4][4], m2u[4][4], su = 0.f;
  #pragma unroll
  for (int gt = 0; gt < 4; ++gt)
    #pragma unroll
    for (int r = 0; r < 4; ++r) {
      int g = gbase + gt * 16 + q * 4 + r;   // C row = q*4 + reg
      bi2[gt][r] = K2 * bias[g];
      float u = uvec[g];
      m2u[gt][r] = -2.f * u;
      su += u;
    }

  f32x4 na = {0.f, 0.f, 0.f, 0.f};     // numerator accum, f = lane*4..+3
  float dacc = 0.f;                    // denom accum (lane 0 of each wave valid)

  for (int it = 0; it < NT; ++it) {
    const int cur = it & 1;
    float* buf = xb[cur];

    // ---- issue next tile's DMAs into the other buffer ----
    if (it + 1 < NT) {
      const float* gp = xt + (long)(it + 1) * TQ * FF + lane * 4;
      float* obuf = xb[cur ^ 1];
      #pragma unroll
      for (int r = 0; r < 8; ++r) {
        int row = wave * 8 + r;
        __builtin_amdgcn_global_load_lds((as1cv)(const void*)(gp + row * FF),
                                         (as3v)(void*)(&obuf[row * RS]), 16, 0, 0);
      }
      wait_barrier<W_VM8>();   // current tile's 8 DMAs done; next 8 stay in flight
    } else {
      wait_barrier<W_VM0>();
    }

    // ---- MFMA: C[g][t]; wave owns g in [64w,64w+64); fp32->bf16 at B-build ----
    f32x4 acc[4][2];
    #pragma unroll
    for (int i = 0; i < 4; ++i) { acc[i][0] = (f32x4){0,0,0,0}; acc[i][1] = (f32x4){0,0,0,0}; }

    #pragma unroll
    for (int kk = 0; kk < 8; ++kk) {
      #pragma unroll
      for (int tt = 0; tt < 2; ++tt) {
        const float* p = &buf[(tt * 16 + ln) * RS + kk * 32 + q * 8];
        f32x4 v0 = *(const f32x4*)p;
        f32x4 v1 = *(const f32x4*)(p + 4);
        union { bf16x8 v; unsigned u[4]; } bb;
        bb.u[0] = pk2bf(v0.x, v0.y); bb.u[1] = pk2bf(v0.z, v0.w);
        bb.u[2] = pk2bf(v1.x, v1.y); bb.u[3] = pk2bf(v1.z, v1.w);
        #pragma unroll
        for (int gt = 0; gt < 4; ++gt)
          acc[gt][tt] = __builtin_amdgcn_mfma_f32_16x16x32_bf16(afr[kk][gt], bb.v, acc[gt][tt], 0, 0, 0);
      }
    }

    // ---- epilogue: ait = su + sum_g m2u[g] * rcp(exp2(fma(C, K2, bi2)) + 1) ----
    #pragma unroll
    for (int tt = 0; tt < 2; ++tt) {
      float s = su;
      #pragma unroll
      for (int gt = 0; gt < 4; ++gt)
        #pragma unroll
        for (int r = 0; r < 4; ++r) {
          float tv = __builtin_fmaf(acc[gt][tt][r], K2, bi2[gt][r]);
          float e1 = __builtin_amdgcn_exp2f(tv) + 1.f;       // inf-safe tanh fold
          s = __builtin_fmaf(m2u[gt][r], __builtin_amdgcn_rcpf(e1), s);
        }
      s += __shfl_xor(s, 16, 64);              // reduce across quads
      s += __shfl_xor(s, 32, 64);
      if (lane < 16) part[wave][tt * 16 + lane] = s;
    }
    wait_barrier<W_LGKM0>();

    // ---- e for this wave's 8 t-rows (redundant per 8 lanes, broadcast reads) ----
    const int tl = wave * 8 + (lane & 7);
    float ait = part[0][tl] + part[1][tl] + part[2][tl] + part[3][tl];
    float e = __expf(ait);
    float dp = (lane < 8) ? e : 0.f;
    dp += __shfl_xor(dp, 1, 64); dp += __shfl_xor(dp, 2, 64); dp += __shfl_xor(dp, 4, 64);
    dacc += dp;                                // lane 0 holds tile's denom partial

    // ---- numerator from fp32 LDS: na += e[t] * x[t][lane*4..+3] ----
    #pragma unroll
    for (int i = 0; i < 8; ++i) {
      float ev = __shfl(e, i, 64);             // e for t = wave*8 + i
      f32x4 xv = *(const f32x4*)(&buf[(wave * 8 + i) * RS + lane * 4]);
      na += xv * ev;
    }
    wait_barrier<W_LGKM0>();   // all reads of buf done before next-next DMA overwrites
  }

  // ---- cross-wave reduce through LDS; per-block partials to ws (no atomics) ----
  __syncthreads();
  float* nred = &xb[0][0];                     // 4 x 256 floats
  *(f32x4*)(&nred[wave * 256 + lane * 4]) = na;
  if (lane == 0) part[wave][0] = dacc;
  __syncthreads();
  {
    float v = nred[tid] + nred[256 + tid] + nred[512 + tid] + nred[768 + tid];
    nump[blockIdx.x * FF + tid] = v;
  }
  if (tid == 0)
    denp[blockIdx.x] = part[0][0] + part[1][0] + part[2][0] + part[3][0];
}

// ---------------- finalize: out[b][f] = sum_seg num / (sum_seg den + eps) ----------------
__global__ void finalize(const float* __restrict__ nump, const float* __restrict__ denp,
                         float* __restrict__ out) {
  int i = blockIdx.x * 256 + threadIdx.x;      // 32768 = b*256 + f
  int b = i >> 8, f = i & 255;
  const float* np = nump + (b * 4) * FF + f;
  float v = np[0] + np[FF] + np[2 * FF] + np[3 * FF];
  const float* dp = denp + b * 4;
  float d = dp[0] + dp[1] + dp[2] + dp[3] + 1e-7f;
  out[i] = v / d;
}

extern "C" void kernel_launch(void* const* d_in, const int* in_sizes, int n_in,
                              void* d_out, int out_size, void* d_ws, size_t ws_size,
                              hipStream_t stream) {
  const float* x  = (const float*)d_in[0];
  const float* W  = (const float*)d_in[1];
  const float* bv = (const float*)d_in[2];
  const float* uv = (const float*)d_in[3];
  float* out = (float*)d_out;

  float* nump = (float*)d_ws;                  // 512 * 256 * 4 = 524288 B
  float* denp = nump + NBLK * FF;              // 512 * 4 B

  attn_main<<<NBLK, 256, 0, stream>>>(x, W, bv, uv, nump, denp);
  finalize<<<BB, 256, 0, stream>>>(nump, denp, out);
}